// Round 1
// baseline (1355.284 us; speedup 1.0000x reference)
//
#include <hip/hip_runtime.h>

// GCNEncoder: 2-layer GCN with self-loops + symmetric norm.
// N=200000 nodes, E=6.4M edges, dims 32->32->16, fp32 everywhere.

__global__ __launch_bounds__(256) void deg_init(float* deg, int n) {
    int i = blockIdx.x * 256 + threadIdx.x;
    if (i < n) deg[i] = 1.0f;  // self-loop
}

__global__ __launch_bounds__(256) void deg_count(const int* __restrict__ dst, float* deg, int E) {
    int e = blockIdx.x * 256 + threadIdx.x;
    if (e < E) atomicAdd(&deg[dst[e]], 1.0f);  // integer-valued: exact
}

__global__ __launch_bounds__(256) void deg_rsqrt(float* deg, int n) {
    int i = blockIdx.x * 256 + threadIdx.x;
    if (i < n) deg[i] = rsqrtf(deg[i]);
}

// hw1 = x @ W1 ; agg1 = b1 + hw1 * dinv^2  (self-loop term pre-seeded)
__global__ __launch_bounds__(256) void transform1(
    const float* __restrict__ x, const float* __restrict__ W1,
    const float* __restrict__ b1, const float* __restrict__ dinv,
    float* __restrict__ hw1, float* __restrict__ agg1, int n) {
    __shared__ float sW[32 * 32];
    __shared__ float sx[8 * 32];
    int tid = threadIdx.x;
    for (int i = tid; i < 1024; i += 256) sW[i] = W1[i];
    int node0 = blockIdx.x * 8;
    int node_ld = node0 + tid / 32;
    sx[tid] = (node_ld < n) ? x[node_ld * 32 + (tid & 31)] : 0.0f;
    __syncthreads();
    int local = tid >> 5;
    int f = tid & 31;
    int node = node0 + local;
    if (node >= n) return;
    float acc = 0.0f;
#pragma unroll
    for (int k = 0; k < 32; ++k) acc += sx[local * 32 + k] * sW[k * 32 + f];
    float di = dinv[node];
    hw1[node * 32 + f] = acc;
    agg1[node * 32 + f] = b1[f] + acc * di * di;
}

// one thread per (edge, feature f<32): gather hw[src]*norm, atomic-add into agg[dst]
__global__ __launch_bounds__(256) void scatter32(
    const int* __restrict__ src, const int* __restrict__ dst,
    const float* __restrict__ dinv, const float* __restrict__ hw,
    float* __restrict__ agg, int E) {
    int gid = blockIdx.x * 256 + threadIdx.x;
    int e = gid >> 5;
    if (e >= E) return;
    int f = gid & 31;
    int s = src[e], d = dst[e];
    float nrm = dinv[s] * dinv[d];
    atomicAdd(&agg[d * 32 + f], hw[s * 32 + f] * nrm);
}

// h1 = relu(agg1); hw2 = h1 @ W2; out = b2 + hw2 * dinv^2
__global__ __launch_bounds__(256) void transform2(
    const float* __restrict__ agg1, const float* __restrict__ W2,
    const float* __restrict__ b2, const float* __restrict__ dinv,
    float* __restrict__ hw2, float* __restrict__ out, int n) {
    __shared__ float sW[32 * 16];
    __shared__ float sh[16 * 32];
    int tid = threadIdx.x;
    for (int i = tid; i < 512; i += 256) sW[i] = W2[i];
    int node0 = blockIdx.x * 16;
    for (int i = tid; i < 512; i += 256) {
        int node = node0 + i / 32;
        sh[i] = (node < n) ? fmaxf(agg1[node * 32 + (i & 31)], 0.0f) : 0.0f;
    }
    __syncthreads();
    int local = tid >> 4;
    int f = tid & 15;
    int node = node0 + local;
    if (node >= n) return;
    float acc = 0.0f;
#pragma unroll
    for (int k = 0; k < 32; ++k) acc += sh[local * 32 + k] * sW[k * 16 + f];
    float di = dinv[node];
    hw2[node * 16 + f] = acc;
    out[node * 16 + f] = b2[f] + acc * di * di;
}

__global__ __launch_bounds__(256) void scatter16(
    const int* __restrict__ src, const int* __restrict__ dst,
    const float* __restrict__ dinv, const float* __restrict__ hw,
    float* __restrict__ out, int E) {
    int gid = blockIdx.x * 256 + threadIdx.x;
    int e = gid >> 4;
    if (e >= E) return;
    int f = gid & 15;
    int s = src[e], d = dst[e];
    float nrm = dinv[s] * dinv[d];
    atomicAdd(&out[d * 16 + f], hw[s * 16 + f] * nrm);
}

extern "C" void kernel_launch(void* const* d_in, const int* in_sizes, int n_in,
                              void* d_out, int out_size, void* d_ws, size_t ws_size,
                              hipStream_t stream) {
    const float* x  = (const float*)d_in[0];
    const int*   ei = (const int*)d_in[1];
    const float* W1 = (const float*)d_in[2];
    const float* b1 = (const float*)d_in[3];
    const float* W2 = (const float*)d_in[4];
    const float* b2 = (const float*)d_in[5];

    int n = in_sizes[0] / 32;  // 200000
    int E = in_sizes[1] / 2;   // 6400000
    const int* src = ei;       // edge_index[0] = message source
    const int* dst = ei + E;   // edge_index[1] = aggregation target

    float* ws   = (float*)d_ws;
    float* dinv = ws;               // n
    float* hw1  = ws + n;           // n*32
    float* agg1 = hw1 + (size_t)n * 32;  // n*32
    float* hw2  = hw1;              // reuse hw1's space (n*16 <= n*32), hw1 dead by then
    float* out  = (float*)d_out;

    deg_init <<<(n + 255) / 256, 256, 0, stream>>>(dinv, n);
    deg_count<<<(E + 255) / 256, 256, 0, stream>>>(dst, dinv, E);
    deg_rsqrt<<<(n + 255) / 256, 256, 0, stream>>>(dinv, n);

    transform1<<<(n + 7) / 8, 256, 0, stream>>>(x, W1, b1, dinv, hw1, agg1, n);
    {
        long long total = (long long)E * 32;
        int blocks = (int)((total + 255) / 256);
        scatter32<<<blocks, 256, 0, stream>>>(src, dst, dinv, hw1, agg1, E);
    }
    transform2<<<(n + 15) / 16, 256, 0, stream>>>(agg1, W2, b2, dinv, hw2, out, n);
    {
        long long total = (long long)E * 16;
        int blocks = (int)((total + 255) / 256);
        scatter16<<<blocks, 256, 0, stream>>>(src, dst, dinv, hw2, out, E);
    }
}

// Round 2
// 1234.174 us; speedup vs baseline: 1.0981x; 1.0981x over previous
//
#include <hip/hip_runtime.h>

// GCNEncoder: 2-layer GCN, pull-based CSR aggregation (no float atomics).
// N=200000, E=6.4M, dims 32->32->16, fp32.
//
// out[d] = b + dinv[d] * ( hws[d] + sum_{j in N(d)} hws[j] ),  hws = (h@W)*dinv[row]

__global__ __launch_bounds__(256) void zero_init(int* deg_i, int* counter, int n) {
    int i = blockIdx.x * 256 + threadIdx.x;
    if (i < n) deg_i[i] = 0;
    if (i == 0) *counter = 0;
}

__global__ __launch_bounds__(256) void deg_count(const int* __restrict__ dst, int* deg_i, int E) {
    int e = blockIdx.x * 256 + threadIdx.x;
    if (e < E) atomicAdd(&deg_i[dst[e]], 1);
}

// Per-node: dinv = rsqrt(deg+1); allocate contiguous CSR segment per node.
// Wave-level prefix scan + ONE atomic per wave (segment order is arbitrary — valid).
__global__ __launch_bounds__(256) void node_setup(
    const int* __restrict__ deg_i, float* __restrict__ dinv,
    int* __restrict__ start, int* __restrict__ cursor,
    int* counter, int n) {
    int i = blockIdx.x * 256 + threadIdx.x;
    int lane = threadIdx.x & 63;
    int dg = (i < n) ? deg_i[i] : 0;
    int v = dg;
#pragma unroll
    for (int o = 1; o < 64; o <<= 1) {
        int t = __shfl_up(v, o);
        if (lane >= o) v += t;
    }
    int total = __shfl(v, 63);
    int base = 0;
    if (lane == 63) base = atomicAdd(counter, total);
    base = __shfl(base, 63);
    if (i < n) {
        int st = base + (v - dg);   // exclusive prefix within wave
        start[i] = st;
        cursor[i] = st;
        dinv[i] = rsqrtf((float)dg + 1.0f);
    }
}

__global__ __launch_bounds__(256) void binning(
    const int* __restrict__ src, const int* __restrict__ dst,
    int* __restrict__ cursor, int* __restrict__ ebuf, int E) {
    int e = blockIdx.x * 256 + threadIdx.x;
    if (e < E) {
        int d = dst[e];
        int p = atomicAdd(&cursor[d], 1);
        ebuf[p] = src[e];
    }
}

// hws1 = (x @ W1) * dinv[row]
__global__ __launch_bounds__(256) void transform1(
    const float* __restrict__ x, const float* __restrict__ W1,
    const float* __restrict__ dinv, float* __restrict__ hws1, int n) {
    __shared__ float sW[32 * 32];
    __shared__ float sx[8 * 32];
    int tid = threadIdx.x;
    for (int i = tid; i < 1024; i += 256) sW[i] = W1[i];
    int node0 = blockIdx.x * 8;
    int node_ld = node0 + tid / 32;
    sx[tid] = (node_ld < n) ? x[node_ld * 32 + (tid & 31)] : 0.0f;
    __syncthreads();
    int local = tid >> 5;
    int f = tid & 31;
    int node = node0 + local;
    if (node >= n) return;
    float acc = 0.0f;
#pragma unroll
    for (int k = 0; k < 32; ++k) acc += sx[local * 32 + k] * sW[k * 32 + f];
    hws1[node * 32 + f] = acc * dinv[node];
}

// h1 = relu(b1 + dinv[d]*(hws1[d] + sum hws1[src]))   -- 8 lanes x float4 per dst
__global__ __launch_bounds__(256) void pull1(
    const int* __restrict__ start, const int* __restrict__ deg_i,
    const int* __restrict__ ebuf, const float* __restrict__ dinv,
    const float* __restrict__ hws1, const float* __restrict__ b1,
    float* __restrict__ h1, int n) {
    int g = threadIdx.x >> 3;
    int lane = threadIdx.x & 7;
    int d = blockIdx.x * 32 + g;
    if (d >= n) return;
    int b = start[d], len = deg_i[d];
    const float4* H = (const float4*)hws1;
    float4 acc = H[(size_t)d * 8 + lane];   // self-loop term
    int j = 0;
    for (; j + 4 <= len; j += 4) {
        int s0 = ebuf[b + j], s1 = ebuf[b + j + 1];
        int s2 = ebuf[b + j + 2], s3 = ebuf[b + j + 3];
        float4 a0 = H[(size_t)s0 * 8 + lane];
        float4 a1 = H[(size_t)s1 * 8 + lane];
        float4 a2 = H[(size_t)s2 * 8 + lane];
        float4 a3 = H[(size_t)s3 * 8 + lane];
        acc.x += (a0.x + a1.x) + (a2.x + a3.x);
        acc.y += (a0.y + a1.y) + (a2.y + a3.y);
        acc.z += (a0.z + a1.z) + (a2.z + a3.z);
        acc.w += (a0.w + a1.w) + (a2.w + a3.w);
    }
    for (; j < len; ++j) {
        float4 a = H[(size_t)ebuf[b + j] * 8 + lane];
        acc.x += a.x; acc.y += a.y; acc.z += a.z; acc.w += a.w;
    }
    float di = dinv[d];
    float4 bb = ((const float4*)b1)[lane];
    float4 o;
    o.x = fmaxf(bb.x + di * acc.x, 0.0f);
    o.y = fmaxf(bb.y + di * acc.y, 0.0f);
    o.z = fmaxf(bb.z + di * acc.z, 0.0f);
    o.w = fmaxf(bb.w + di * acc.w, 0.0f);
    ((float4*)h1)[(size_t)d * 8 + lane] = o;
}

// hws2 = (h1 @ W2) * dinv[row]   (h1 already relu'd)
__global__ __launch_bounds__(256) void transform2(
    const float* __restrict__ h1, const float* __restrict__ W2,
    const float* __restrict__ dinv, float* __restrict__ hws2, int n) {
    __shared__ float sW[32 * 16];
    __shared__ float sh[16 * 32];
    int tid = threadIdx.x;
    for (int i = tid; i < 512; i += 256) sW[i] = W2[i];
    int node0 = blockIdx.x * 16;
    for (int i = tid; i < 512; i += 256) {
        int node = node0 + i / 32;
        sh[i] = (node < n) ? h1[node * 32 + (i & 31)] : 0.0f;
    }
    __syncthreads();
    int local = tid >> 4;
    int f = tid & 15;
    int node = node0 + local;
    if (node >= n) return;
    float acc = 0.0f;
#pragma unroll
    for (int k = 0; k < 32; ++k) acc += sh[local * 32 + k] * sW[k * 16 + f];
    hws2[node * 16 + f] = acc * dinv[node];
}

// out = b2 + dinv[d]*(hws2[d] + sum hws2[src])   -- 4 lanes x float4 per dst
__global__ __launch_bounds__(256) void pull2(
    const int* __restrict__ start, const int* __restrict__ deg_i,
    const int* __restrict__ ebuf, const float* __restrict__ dinv,
    const float* __restrict__ hws2, const float* __restrict__ b2,
    float* __restrict__ out, int n) {
    int g = threadIdx.x >> 2;
    int lane = threadIdx.x & 3;
    int d = blockIdx.x * 64 + g;
    if (d >= n) return;
    int b = start[d], len = deg_i[d];
    const float4* H = (const float4*)hws2;
    float4 acc = H[(size_t)d * 4 + lane];   // self-loop term
    int j = 0;
    for (; j + 4 <= len; j += 4) {
        int s0 = ebuf[b + j], s1 = ebuf[b + j + 1];
        int s2 = ebuf[b + j + 2], s3 = ebuf[b + j + 3];
        float4 a0 = H[(size_t)s0 * 4 + lane];
        float4 a1 = H[(size_t)s1 * 4 + lane];
        float4 a2 = H[(size_t)s2 * 4 + lane];
        float4 a3 = H[(size_t)s3 * 4 + lane];
        acc.x += (a0.x + a1.x) + (a2.x + a3.x);
        acc.y += (a0.y + a1.y) + (a2.y + a3.y);
        acc.z += (a0.z + a1.z) + (a2.z + a3.z);
        acc.w += (a0.w + a1.w) + (a2.w + a3.w);
    }
    for (; j < len; ++j) {
        float4 a = H[(size_t)ebuf[b + j] * 4 + lane];
        acc.x += a.x; acc.y += a.y; acc.z += a.z; acc.w += a.w;
    }
    float di = dinv[d];
    float4 bb = ((const float4*)b2)[lane];
    float4 o;
    o.x = bb.x + di * acc.x;
    o.y = bb.y + di * acc.y;
    o.z = bb.z + di * acc.z;
    o.w = bb.w + di * acc.w;
    ((float4*)out)[(size_t)d * 4 + lane] = o;
}

extern "C" void kernel_launch(void* const* d_in, const int* in_sizes, int n_in,
                              void* d_out, int out_size, void* d_ws, size_t ws_size,
                              hipStream_t stream) {
    const float* x  = (const float*)d_in[0];
    const int*   ei = (const int*)d_in[1];
    const float* W1 = (const float*)d_in[2];
    const float* b1 = (const float*)d_in[3];
    const float* W2 = (const float*)d_in[4];
    const float* b2 = (const float*)d_in[5];

    int n = in_sizes[0] / 32;  // 200000
    int E = in_sizes[1] / 2;   // 6400000
    const int* src = ei;
    const int* dst = ei + E;

    char* w = (char*)d_ws;
    int*   deg_i   = (int*)w;                 w += (size_t)n * 4;
    float* dinv    = (float*)w;               w += (size_t)n * 4;
    int*   start   = (int*)w;                 w += (size_t)n * 4;
    int*   cursor  = (int*)w;                 w += (size_t)n * 4;
    int*   counter = (int*)w;                 w += 64;   // pad for alignment
    int*   ebuf    = (int*)w;                 w += (size_t)E * 4;
    float* hws1    = (float*)w;               w += (size_t)n * 32 * 4;
    float* h1      = (float*)w;               w += (size_t)n * 32 * 4;
    float* hws2    = hws1;  // hws1 dead after pull1
    float* out     = (float*)d_out;

    zero_init <<<(n + 256) / 256, 256, 0, stream>>>(deg_i, counter, n);
    deg_count <<<(E + 255) / 256, 256, 0, stream>>>(dst, deg_i, E);
    node_setup<<<(n + 255) / 256, 256, 0, stream>>>(deg_i, dinv, start, cursor, counter, n);
    binning   <<<(E + 255) / 256, 256, 0, stream>>>(src, dst, cursor, ebuf, E);

    transform1<<<(n + 7) / 8, 256, 0, stream>>>(x, W1, dinv, hws1, n);
    pull1     <<<(n + 31) / 32, 256, 0, stream>>>(start, deg_i, ebuf, dinv, hws1, b1, h1, n);
    transform2<<<(n + 15) / 16, 256, 0, stream>>>(h1, W2, dinv, hws2, n);
    pull2     <<<(n + 63) / 64, 256, 0, stream>>>(start, deg_i, ebuf, dinv, hws2, b2, out, n);
}